// Round 7
// baseline (205.713 us; speedup 1.0000x reference)
//
#include <hip/hip_runtime.h>

typedef __bf16 bf16;
typedef __attribute__((ext_vector_type(8))) __bf16 bf16x8;
typedef __attribute__((ext_vector_type(4))) __bf16 bf16x4;
typedef __attribute__((ext_vector_type(2))) __bf16 bf16x2;
typedef __attribute__((ext_vector_type(4))) float f32x4;

#define MFMA(a, b, c) __builtin_amdgcn_mfma_f32_16x16x32_bf16((a), (b), (c), 0, 0, 0)
#define LOG2E 1.44269504088896340736f

__device__ __forceinline__ bf16x8 cvt8(float4 a, float4 b) {
  bf16x8 r;
  r[0] = (bf16)a.x; r[1] = (bf16)a.y; r[2] = (bf16)a.z; r[3] = (bf16)a.w;
  r[4] = (bf16)b.x; r[5] = (bf16)b.y; r[6] = (bf16)b.z; r[7] = (bf16)b.w;
  return r;
}

__device__ __forceinline__ int pk2(float x, float y) {
  union { bf16x2 h; int i; } u;
  u.h[0] = (bf16)x; u.h[1] = (bf16)y;
  return u.i;
}

// async global->LDS, 16B per lane. LDS dest = wave-uniform base + lane*16.
__device__ __forceinline__ void stage16(const bf16* g, bf16* l) {
  __builtin_amdgcn_global_load_lds(
      (const __attribute__((address_space(1))) void*)g,
      (__attribute__((address_space(3))) void*)l, 16, 0, 0);
}

// ---------------------------------------------------------------------------
// Kernel 0: cast X -> bf16; cast+transpose W -> bf16 W^T[n][k] (3 matrices).
// ---------------------------------------------------------------------------
__global__ __launch_bounds__(256)
void cvt(const float* __restrict__ hs, const float* __restrict__ qw,
         const float* __restrict__ kw, const float* __restrict__ vw,
         bf16* __restrict__ Xb, bf16* __restrict__ Wt) {
  const int bid = blockIdx.x, tid = threadIdx.x;
  if (bid < 2048) {               // X: 4096x1024 fp32 -> bf16, 8 elems/thread
    size_t off = (size_t)bid * 2048 + tid * 8;
    float4 x0 = *(const float4*)(hs + off);
    float4 x1 = *(const float4*)(hs + off + 4);
    *(bf16x8*)(Xb + off) = cvt8(x0, x1);
  } else {                        // W transpose: 64x64 tiles via LDS
    int t = bid - 2048;           // 0..767
    int z = t >> 8, ti = t & 255;
    const float* W = (z == 0) ? qw : (z == 1) ? kw : vw;
    int k0 = (ti >> 4) * 64, n0 = (ti & 15) * 64;
    __shared__ bf16 T[64 * 72];   // [n][k], pad 72
    #pragma unroll
    for (int i = 0; i < 16; ++i) {
      int e = i * 256 + tid;
      int kr = e >> 6, nc = e & 63;
      T[nc * 72 + kr] = (bf16)W[(size_t)(k0 + kr) * 1024 + n0 + nc];
    }
    __syncthreads();
    #pragma unroll
    for (int i = 0; i < 2; ++i) {
      int e = i * 256 + tid;
      int nr = e >> 3, kg = e & 7;
      *(bf16x8*)(Wt + (size_t)z * 1048576 + (size_t)(n0 + nr) * 1024 + k0 + kg * 8) =
          *(const bf16x8*)&T[nr * 72 + kg * 8];
    }
  }
}

// ---------------------------------------------------------------------------
// Kernel 1: QKV GEMM — m97 shape: 128x128 tile, 4 waves 2x2, BK=32,
// global_load_lds w=16, granule-XOR swizzle on the global-address side.
// 768 blocks = one clean round at 3/CU. XCD swizzle: mb-band per XCD.
// Q pre-scaled by 0.125*log2e. V stored TRANSPOSED [B,H,64,S].
// (unchanged from R6 — correct, stable)
// ---------------------------------------------------------------------------
__global__ __launch_bounds__(256, 3)
void qkv_gemm(const bf16* __restrict__ Xb, const bf16* __restrict__ Wt,
              const float* __restrict__ qbias, const float* __restrict__ kbias,
              const float* __restrict__ vbias,
              bf16* __restrict__ qo, bf16* __restrict__ ko, bf16* __restrict__ vo) {
  const int blk = blockIdx.x;                 // 0..767
  const int xcd = blk & 7, slot = blk >> 3;   // slot 0..95
  const int mb = xcd * 4 + slot / 24;         // 0..31
  const int nb = slot % 24;                   // 0..23
  const int z = nb >> 3, nbm = nb & 7;
  const bf16* W = Wt + (size_t)z * 1048576;

  const int tid = threadIdx.x;
  const int wave = tid >> 6, lane = tid & 63, quad = lane >> 4, c = lane & 15;
  const int wr = wave >> 1, wc = wave & 1;
  const int r4 = lane >> 2;                   // 0..15: row within 16-row group
  const int g4 = (lane & 3) ^ (r4 & 3);       // swizzled source granule (4/row)

  __shared__ bf16 As[128 * 32];               // [m][k], granule g stored at g^(m&3)
  __shared__ bf16 Bs[128 * 32];               // [n][k], same swizzle

  const bf16* aS0 = Xb + (size_t)(mb * 128 + wave * 16 + r4) * 1024 + g4 * 8;
  const bf16* aS1 = aS0 + (size_t)64 * 1024;
  const bf16* bS0 = W + (size_t)(nbm * 128 + wave * 16 + r4) * 1024 + g4 * 8;
  const bf16* bS1 = bS0 + (size_t)64 * 1024;
  bf16* aD0 = &As[(wave * 16) * 32];
  bf16* aD1 = &As[(64 + wave * 16) * 32];
  bf16* bD0 = &Bs[(wave * 16) * 32];
  bf16* bD1 = &Bs[(64 + wave * 16) * 32];

  int aOff[4], bOff[4];
  #pragma unroll
  for (int t = 0; t < 4; ++t) {
    aOff[t] = (wr * 64 + t * 16 + c) * 32 + ((quad ^ (c & 3)) << 3);
    bOff[t] = (wc * 64 + t * 16 + c) * 32 + ((quad ^ (c & 3)) << 3);
  }

  f32x4 acc[4][4] = {};

  for (int k0 = 0; k0 < 1024; k0 += 32) {
    stage16(aS0 + k0, aD0);
    stage16(aS1 + k0, aD1);
    stage16(bS0 + k0, bD0);
    stage16(bS1 + k0, bD1);
    __syncthreads();
    bf16x8 af[4];
    #pragma unroll
    for (int rt = 0; rt < 4; ++rt) af[rt] = *(const bf16x8*)&As[aOff[rt]];
    #pragma unroll
    for (int nt = 0; nt < 4; ++nt) {
      bf16x8 bfrag = *(const bf16x8*)&Bs[bOff[nt]];
      #pragma unroll
      for (int rt = 0; rt < 4; ++rt)
        acc[rt][nt] = MFMA(af[rt], bfrag, acc[rt][nt]);
    }
    __syncthreads();
  }

  const float* bias = (z == 0) ? qbias : (z == 1) ? kbias : vbias;
  float bv[4];
  #pragma unroll
  for (int nt = 0; nt < 4; ++nt)
    bv[nt] = bias[nbm * 128 + wc * 64 + nt * 16 + c];

  if (z == 2) {
    // V^T: vo[((b*16+h)*64 + d)*2048 + s], packed 4 along s (= reg dim)
    #pragma unroll
    for (int rt = 0; rt < 4; ++rt)
      #pragma unroll
      for (int nt = 0; nt < 4; ++nt) {
        int m0 = mb * 128 + wr * 64 + rt * 16 + 4 * quad;
        int n = nbm * 128 + wc * 64 + nt * 16 + c;
        bf16x4 pk;
        #pragma unroll
        for (int reg = 0; reg < 4; ++reg) pk[reg] = (bf16)(acc[rt][nt][reg] + bv[nt]);
        int b = m0 >> 11, s0 = m0 & 2047, h = n >> 6, d = n & 63;
        *(bf16x4*)&vo[(((size_t)b * 16 + h) * 64 + d) * 2048 + s0] = pk;
      }
  } else {
    bf16* dst = (z == 0) ? qo : ko;
    const float scale = (z == 0) ? 0.125f * LOG2E : 1.0f;
    #pragma unroll
    for (int rt = 0; rt < 4; ++rt)
      #pragma unroll
      for (int nt = 0; nt < 4; ++nt)
        #pragma unroll
        for (int reg = 0; reg < 4; ++reg) {
          float v = (acc[rt][nt][reg] + bv[nt]) * scale;
          int m = mb * 128 + wr * 64 + rt * 16 + 4 * quad + reg;
          int n = nbm * 128 + wc * 64 + nt * 16 + c;
          int b = m >> 11, s = m & 2047, h = n >> 6, d = n & 63;
          dst[(((size_t)b * 16 + h) * 2048 + s) * 64 + d] = (bf16)v;
        }
  }
}

// ---------------------------------------------------------------------------
// Kernel 2: attention — LDS-op-minimized. S^T = K·Q^T (key in reg dim, q in
// lane dim) and O^T = V^T·P^T, so:
//  - P^T spills to LDS as 8 ds_write_b64 (reg-consecutive keys), read back
//    as 4 ds_read_b128 B-frags; b64 XOR swizzle g^=(c&7)<<1 is conflict-free.
//  - lsum is a pure in-lane scalar (q = lane's c); 2 shuffles at the end.
//  - epilogue: in-lane normalize + 8 float4 stores.
// rt=2 (32 q-rows/wave): K/V frag reads amortized over 2x MFMA.
// 4 waves x 32 rows = 128 q-rows/WG, 512 WGs, 2 blocks/CU. XCD-pinned K/V.
// Per-wave-ktile: 20 ds_read_b128 + 8 ds_write_b64 + 32 MFMA (was 18+16sc+16).
// ---------------------------------------------------------------------------
__global__ __launch_bounds__(256, 2)
void attn(const bf16* __restrict__ qg, const bf16* __restrict__ kg,
          const bf16* __restrict__ vtg, const float* __restrict__ mask,
          float* __restrict__ out) {
  const int blk = blockIdx.x;                // 0..511
  const int xcd = blk & 7, slot = blk >> 3;  // slot 0..63
  const int bh = xcd * 4 + (slot >> 4);      // 4 bh per XCD
  const int qblk = slot & 15;                // 128 q-rows each
  const int b = bh >> 4, h = bh & 15;
  const int tid = threadIdx.x;
  const int wave = tid >> 6, lane = tid & 63, quad = lane >> 4, c = lane & 15;
  const int lrow = lane >> 3, lg = (lane & 7) ^ lrow;

  __shared__ bf16 Ks[64 * 64];    // [key][d], 16B-granule swizzle by key&7
  __shared__ bf16 Vs[64 * 64];    // [d][key], 16B-granule swizzle by d&7
  __shared__ bf16 Ps[128 * 64];   // P^T as [q_local][key], 8B-granule swizzle

  const bf16* qb_ = qg + (size_t)bh * 2048 * 64;
  const bf16* kb_ = kg + (size_t)bh * 2048 * 64;
  const bf16* vb_ = vtg + (size_t)bh * 64 * 2048;
  const float* mk_ = mask + (size_t)b * 2048;

  bf16x8 qf[2][2];   // Q pre-scaled by 0.125*log2e: [rt][ch], q-row = c
  #pragma unroll
  for (int rt = 0; rt < 2; ++rt)
    #pragma unroll
    for (int ch = 0; ch < 2; ++ch)
      qf[rt][ch] = *(const bf16x8*)(qb_ +
          (size_t)(qblk * 128 + wave * 32 + rt * 16 + c) * 64 + ch * 32 + quad * 8);

  const int sw2 = (c & 7) << 1;   // b64-granule XOR swizzle for Ps
  f32x4 o[2][4] = {};
  float lsum[2] = {0.f, 0.f};

  for (int kt = 0; kt < 32; ++kt) {
    #pragma unroll
    for (int i = 0; i < 2; ++i) {  // stage K [64 keys][64 d], V [64 d][64 keys]
      int r = wave * 16 + i * 8;
      stage16(kb_ + (size_t)(kt * 64 + r + lrow) * 64 + lg * 8, &Ks[r * 64]);
      stage16(vb_ + (size_t)(r + lrow) * 2048 + kt * 64 + lg * 8, &Vs[r * 64]);
    }
    __syncthreads();

    // ---- S^T = K Q^T: row = key (nt*16 + 4quad + reg), col = q (c) ----
    f32x4 s[2][4] = {};
    #pragma unroll
    for (int nt = 0; nt < 4; ++nt)
      #pragma unroll
      for (int ch = 0; ch < 2; ++ch) {
        bf16x8 kf = *(const bf16x8*)&Ks[(nt * 16 + c) * 64 +
                                        ((((ch << 2) | quad) ^ (c & 7)) << 3)];
        #pragma unroll
        for (int rt = 0; rt < 2; ++rt)
          s[rt][nt] = MFMA(kf, qf[rt][ch], s[rt][nt]);
      }

    // ---- p = exp2(s + mask[key]*log2e); in-lane lsum; b64 spill of P^T ----
    #pragma unroll
    for (int rt = 0; rt < 2; ++rt)
      #pragma unroll
      for (int nt = 0; nt < 4; ++nt) {
        float4 mv = *(const float4*)&mk_[kt * 64 + nt * 16 + 4 * quad];
        float p0 = __builtin_amdgcn_exp2f(fmaf(mv.x, LOG2E, s[rt][nt][0]));
        float p1 = __builtin_amdgcn_exp2f(fmaf(mv.y, LOG2E, s[rt][nt][1]));
        float p2 = __builtin_amdgcn_exp2f(fmaf(mv.z, LOG2E, s[rt][nt][2]));
        float p3 = __builtin_amdgcn_exp2f(fmaf(mv.w, LOG2E, s[rt][nt][3]));
        lsum[rt] += (p0 + p1) + (p2 + p3);
        int gp = (nt * 4 + quad) ^ sw2;   // b64 granule, swizzled
        int2 w = {pk2(p0, p1), pk2(p2, p3)};
        *(int2*)&Ps[(wave * 32 + rt * 16 + c) * 64 + gp * 4] = w;
      }
    __asm__ volatile("s_waitcnt lgkmcnt(0)" ::: "memory");  // wave-private order

    // ---- O^T += V^T P^T: A = V^T frag (shared over rt), B = P^T frag ----
    #pragma unroll
    for (int ch = 0; ch < 2; ++ch) {
      bf16x8 pb[2];
      #pragma unroll
      for (int rt = 0; rt < 2; ++rt) {
        int gp = (ch * 8 + 2 * quad) ^ sw2;   // even b64 granule -> b128 ok
        pb[rt] = *(const bf16x8*)&Ps[(wave * 32 + rt * 16 + c) * 64 + gp * 4];
      }
      #pragma unroll
      for (int nt = 0; nt < 4; ++nt) {
        bf16x8 vf = *(const bf16x8*)&Vs[(nt * 16 + c) * 64 +
                                        ((((ch << 2) | quad) ^ (c & 7)) << 3)];
        #pragma unroll
        for (int rt = 0; rt < 2; ++rt)
          o[rt][nt] = MFMA(vf, pb[rt], o[rt][nt]);
      }
    }
    __syncthreads();
  }

  // ---- epilogue: in-lane l (reduce over quads), normalize, float4 store ----
  #pragma unroll
  for (int rt = 0; rt < 2; ++rt) {
    float l = lsum[rt];
    l += __shfl_xor(l, 16, 64);
    l += __shfl_xor(l, 32, 64);
    float inv = 1.0f / l;
    int q = qblk * 128 + wave * 32 + rt * 16 + c;
    float* op = out + ((size_t)b * 2048 + q) * 1024 + h * 64;
    #pragma unroll
    for (int nt = 0; nt < 4; ++nt) {
      float4 v = {o[rt][nt][0] * inv, o[rt][nt][1] * inv,
                  o[rt][nt][2] * inv, o[rt][nt][3] * inv};
      *(float4*)&op[nt * 16 + 4 * quad] = v;
    }
  }
}

// ---------------------------------------------------------------------------
extern "C" void kernel_launch(void* const* d_in, const int* in_sizes, int n_in,
                              void* d_out, int out_size, void* d_ws, size_t ws_size,
                              hipStream_t stream) {
  const float* hs   = (const float*)d_in[0];
  const float* mask = (const float*)d_in[1];
  const float* qw   = (const float*)d_in[2];
  const float* qb   = (const float*)d_in[3];
  const float* kw   = (const float*)d_in[4];
  const float* kb   = (const float*)d_in[5];
  const float* vw   = (const float*)d_in[6];
  const float* vb   = (const float*)d_in[7];
  float* out = (float*)d_out;

  bf16* Xb   = (bf16*)d_ws;                       // 4096x1024      (8 MB)
  bf16* Wt   = Xb + (size_t)4096 * 1024;          // 3x1024x1024    (6 MB)
  bf16* q_ws = Wt + (size_t)3 * 1048576;          // [B,H,S,64]     (8 MB)
  bf16* k_ws = q_ws + (size_t)4096 * 1024;        // [B,H,S,64]     (8 MB)
  bf16* v_ws = k_ws + (size_t)4096 * 1024;        // [B,H,64,S] V^T (8 MB)

  cvt<<<dim3(2816), 256, 0, stream>>>(hs, qw, kw, vw, Xb, Wt);
  qkv_gemm<<<dim3(768), 256, 0, stream>>>(Xb, Wt, qb, kb, vb, q_ws, k_ws, v_ws);
  attn<<<dim3(512), 256, 0, stream>>>(q_ws, k_ws, v_ws, mask, out);
}

// Round 8
// 185.959 us; speedup vs baseline: 1.1062x; 1.1062x over previous
//
#include <hip/hip_runtime.h>

typedef __bf16 bf16;
typedef __attribute__((ext_vector_type(8))) __bf16 bf16x8;
typedef __attribute__((ext_vector_type(4))) __bf16 bf16x4;
typedef __attribute__((ext_vector_type(4))) float f32x4;

#define MFMA(a, b, c) __builtin_amdgcn_mfma_f32_16x16x32_bf16((a), (b), (c), 0, 0, 0)
#define LOG2E 1.44269504088896340736f

__device__ __forceinline__ bf16x8 cvt8(float4 a, float4 b) {
  bf16x8 r;
  r[0] = (bf16)a.x; r[1] = (bf16)a.y; r[2] = (bf16)a.z; r[3] = (bf16)a.w;
  r[4] = (bf16)b.x; r[5] = (bf16)b.y; r[6] = (bf16)b.z; r[7] = (bf16)b.w;
  return r;
}

// async global->LDS, 16B per lane. LDS dest = wave-uniform base + lane*16.
__device__ __forceinline__ void stage16(const bf16* g, bf16* l) {
  __builtin_amdgcn_global_load_lds(
      (const __attribute__((address_space(1))) void*)g,
      (__attribute__((address_space(3))) void*)l, 16, 0, 0);
}

// ---------------------------------------------------------------------------
// Kernel 0: cast X -> bf16; cast+transpose W -> bf16 W^T[n][k] (3 matrices).
// ---------------------------------------------------------------------------
__global__ __launch_bounds__(256)
void cvt(const float* __restrict__ hs, const float* __restrict__ qw,
         const float* __restrict__ kw, const float* __restrict__ vw,
         bf16* __restrict__ Xb, bf16* __restrict__ Wt) {
  const int bid = blockIdx.x, tid = threadIdx.x;
  if (bid < 2048) {               // X: 4096x1024 fp32 -> bf16, 8 elems/thread
    size_t off = (size_t)bid * 2048 + tid * 8;
    float4 x0 = *(const float4*)(hs + off);
    float4 x1 = *(const float4*)(hs + off + 4);
    *(bf16x8*)(Xb + off) = cvt8(x0, x1);
  } else {                        // W transpose: 64x64 tiles via LDS
    int t = bid - 2048;           // 0..767
    int z = t >> 8, ti = t & 255;
    const float* W = (z == 0) ? qw : (z == 1) ? kw : vw;
    int k0 = (ti >> 4) * 64, n0 = (ti & 15) * 64;
    __shared__ bf16 T[64 * 72];   // [n][k], pad 72
    #pragma unroll
    for (int i = 0; i < 16; ++i) {
      int e = i * 256 + tid;
      int kr = e >> 6, nc = e & 63;
      T[nc * 72 + kr] = (bf16)W[(size_t)(k0 + kr) * 1024 + n0 + nc];
    }
    __syncthreads();
    #pragma unroll
    for (int i = 0; i < 2; ++i) {
      int e = i * 256 + tid;
      int nr = e >> 3, kg = e & 7;
      *(bf16x8*)(Wt + (size_t)z * 1048576 + (size_t)(n0 + nr) * 1024 + k0 + kg * 8) =
          *(const bf16x8*)&T[nr * 72 + kg * 8];
    }
  }
}

// ---------------------------------------------------------------------------
// Kernel 1: QKV GEMM — m97 shape + LDS DOUBLE-BUFFER (one barrier per
// K-step instead of two; staging for k+32 flies behind compute of k).
// 128x128 tile, 4 waves 2x2, BK=32, global_load_lds w=16, granule-XOR
// swizzle on the global-address side. 768 blocks = one round at 3/CU.
// XCD swizzle: mb-band per XCD. Q pre-scaled 0.125*log2e. V stored ^T.
// ---------------------------------------------------------------------------
__global__ __launch_bounds__(256, 3)
void qkv_gemm(const bf16* __restrict__ Xb, const bf16* __restrict__ Wt,
              const float* __restrict__ qbias, const float* __restrict__ kbias,
              const float* __restrict__ vbias,
              bf16* __restrict__ qo, bf16* __restrict__ ko, bf16* __restrict__ vo) {
  const int blk = blockIdx.x;                 // 0..767
  const int xcd = blk & 7, slot = blk >> 3;   // slot 0..95
  const int mb = xcd * 4 + slot / 24;         // 0..31
  const int nb = slot % 24;                   // 0..23
  const int z = nb >> 3, nbm = nb & 7;
  const bf16* W = Wt + (size_t)z * 1048576;

  const int tid = threadIdx.x;
  const int wave = tid >> 6, lane = tid & 63, quad = lane >> 4, c = lane & 15;
  const int wr = wave >> 1, wc = wave & 1;
  const int r4 = lane >> 2;                   // 0..15: row within 16-row group
  const int g4 = (lane & 3) ^ (r4 & 3);       // swizzled source granule (4/row)

  __shared__ bf16 As[2][128 * 32];            // [m][k], granule g at g^(m&3)
  __shared__ bf16 Bs[2][128 * 32];            // [n][k], same swizzle

  const bf16* aS0 = Xb + (size_t)(mb * 128 + wave * 16 + r4) * 1024 + g4 * 8;
  const bf16* aS1 = aS0 + (size_t)64 * 1024;
  const bf16* bS0 = W + (size_t)(nbm * 128 + wave * 16 + r4) * 1024 + g4 * 8;
  const bf16* bS1 = bS0 + (size_t)64 * 1024;
  const int d0 = (wave * 16) * 32, d1 = (64 + wave * 16) * 32;

  int aOff[4], bOff[4];
  #pragma unroll
  for (int t = 0; t < 4; ++t) {
    aOff[t] = (wr * 64 + t * 16 + c) * 32 + ((quad ^ (c & 3)) << 3);
    bOff[t] = (wc * 64 + t * 16 + c) * 32 + ((quad ^ (c & 3)) << 3);
  }

  f32x4 acc[4][4] = {};

  // prologue: stage k=0 into buffer 0
  stage16(aS0, &As[0][d0]);
  stage16(aS1, &As[0][d1]);
  stage16(bS0, &Bs[0][d0]);
  stage16(bS1, &Bs[0][d1]);

  for (int k0 = 0; k0 < 1024; k0 += 32) {
    __syncthreads();                          // buf staged; other buf free
    const int buf = (k0 >> 5) & 1;
    if (k0 < 992) {                           // stage k0+32 into buf^1
      stage16(aS0 + k0 + 32, &As[buf ^ 1][d0]);
      stage16(aS1 + k0 + 32, &As[buf ^ 1][d1]);
      stage16(bS0 + k0 + 32, &Bs[buf ^ 1][d0]);
      stage16(bS1 + k0 + 32, &Bs[buf ^ 1][d1]);
    }
    bf16x8 af[4];
    #pragma unroll
    for (int rt = 0; rt < 4; ++rt) af[rt] = *(const bf16x8*)&As[buf][aOff[rt]];
    #pragma unroll
    for (int nt = 0; nt < 4; ++nt) {
      bf16x8 bfrag = *(const bf16x8*)&Bs[buf][bOff[nt]];
      #pragma unroll
      for (int rt = 0; rt < 4; ++rt)
        acc[rt][nt] = MFMA(af[rt], bfrag, acc[rt][nt]);
    }
  }

  const float* bias = (z == 0) ? qbias : (z == 1) ? kbias : vbias;
  float bv[4];
  #pragma unroll
  for (int nt = 0; nt < 4; ++nt)
    bv[nt] = bias[nbm * 128 + wc * 64 + nt * 16 + c];

  if (z == 2) {
    // V^T: vo[((b*16+h)*64 + d)*2048 + s], packed 4 along s (= reg dim)
    #pragma unroll
    for (int rt = 0; rt < 4; ++rt)
      #pragma unroll
      for (int nt = 0; nt < 4; ++nt) {
        int m0 = mb * 128 + wr * 64 + rt * 16 + 4 * quad;
        int n = nbm * 128 + wc * 64 + nt * 16 + c;
        bf16x4 pk;
        #pragma unroll
        for (int reg = 0; reg < 4; ++reg) pk[reg] = (bf16)(acc[rt][nt][reg] + bv[nt]);
        int b = m0 >> 11, s0 = m0 & 2047, h = n >> 6, d = n & 63;
        *(bf16x4*)&vo[(((size_t)b * 16 + h) * 64 + d) * 2048 + s0] = pk;
      }
  } else {
    bf16* dst = (z == 0) ? qo : ko;
    const float scale = (z == 0) ? 0.125f * LOG2E : 1.0f;
    #pragma unroll
    for (int rt = 0; rt < 4; ++rt)
      #pragma unroll
      for (int nt = 0; nt < 4; ++nt)
        #pragma unroll
        for (int reg = 0; reg < 4; ++reg) {
          float v = (acc[rt][nt][reg] + bv[nt]) * scale;
          int m = mb * 128 + wr * 64 + rt * 16 + 4 * quad + reg;
          int n = nbm * 128 + wc * 64 + nt * 16 + c;
          int b = m >> 11, s = m & 2047, h = n >> 6, d = n & 63;
          dst[(((size_t)b * 16 + h) * 2048 + s) * 64 + d] = (bf16)v;
        }
  }
}

// ---------------------------------------------------------------------------
// Kernel 2: attention — R6's measured-0-conflict LDS patterns, rt=2
// (32 q-rows/wave: K/V b128 frag reads amortized over 2x MFMA) + K/V
// double-buffer (stage kt+1 behind compute of kt; one barrier per ktile).
// 4 waves x 32 rows = 128 q-rows/WG, 512 WGs (2 blocks/CU). XCD-pinned K/V.
// Per-wave-ktile: 20 ds_read_b128 + 32 ds_write_b16 + 32 MFMA (~416 LDS cyc
// for 2x the work of R3's 312) -> model floor ~44 us.
// ---------------------------------------------------------------------------
__global__ __launch_bounds__(256, 2)
void attn(const bf16* __restrict__ qg, const bf16* __restrict__ kg,
          const bf16* __restrict__ vtg, const float* __restrict__ mask,
          float* __restrict__ out) {
  const int blk = blockIdx.x;                // 0..511
  const int xcd = blk & 7, slot = blk >> 3;  // slot 0..63
  const int bh = xcd * 4 + (slot >> 4);      // 4 bh per XCD
  const int qblk = slot & 15;                // 128 q-rows each
  const int b = bh >> 4, h = bh & 15;
  const int tid = threadIdx.x;
  const int wave = tid >> 6, lane = tid & 63, quad = lane >> 4, c = lane & 15;
  const int lrow = lane >> 3, lg = (lane & 7) ^ lrow;

  __shared__ bf16 Ks[2][64 * 64];   // [key][d], 16B-granule swizzle by key&7
  __shared__ bf16 Vs[2][64 * 64];   // [d][key], 16B-granule swizzle by d&7
  __shared__ bf16 Ps[4][2048];      // per-wave P: 2 x 16 rows x 64 keys

  const bf16* qb_ = qg + (size_t)bh * 2048 * 64;
  const bf16* kb_ = kg + (size_t)bh * 2048 * 64;
  const bf16* vb_ = vtg + (size_t)bh * 64 * 2048;
  const float* mk_ = mask + (size_t)b * 2048;

  bf16x8 qf[2][2];   // Q pre-scaled by 0.125*log2e; wave owns 32 rows
  #pragma unroll
  for (int rt = 0; rt < 2; ++rt)
    #pragma unroll
    for (int ch = 0; ch < 2; ++ch)
      qf[rt][ch] = *(const bf16x8*)(qb_ +
          (size_t)(qblk * 128 + wave * 32 + rt * 16 + c) * 64 + ch * 32 + quad * 8);

  f32x4 o[2][4] = {};
  float lsum[2][4] = {};

  {  // prologue: stage tile 0 into buffer 0
    int r = wave * 16;
    stage16(kb_ + (size_t)(r + lrow) * 64 + lg * 8, &Ks[0][r * 64]);
    stage16(kb_ + (size_t)(r + 8 + lrow) * 64 + lg * 8, &Ks[0][(r + 8) * 64]);
    stage16(vb_ + (size_t)(r + lrow) * 2048 + lg * 8, &Vs[0][r * 64]);
    stage16(vb_ + (size_t)(r + 8 + lrow) * 2048 + lg * 8, &Vs[0][(r + 8) * 64]);
  }

  for (int kt = 0; kt < 32; ++kt) {
    __syncthreads();             // tile kt staged; buf^1 free for overwrite
    const int cur = kt & 1;
    if (kt < 31) {               // stage kt+1 into the other buffer
      int r = wave * 16;
      stage16(kb_ + (size_t)((kt + 1) * 64 + r + lrow) * 64 + lg * 8,
              &Ks[cur ^ 1][r * 64]);
      stage16(kb_ + (size_t)((kt + 1) * 64 + r + 8 + lrow) * 64 + lg * 8,
              &Ks[cur ^ 1][(r + 8) * 64]);
      stage16(vb_ + (size_t)(r + lrow) * 2048 + (kt + 1) * 64 + lg * 8,
              &Vs[cur ^ 1][r * 64]);
      stage16(vb_ + (size_t)(r + 8 + lrow) * 2048 + (kt + 1) * 64 + lg * 8,
              &Vs[cur ^ 1][(r + 8) * 64]);
    }

    // ---- S = Q K^T: K-frags shared across rt ----
    f32x4 s[2][4] = {};
    #pragma unroll
    for (int nt = 0; nt < 4; ++nt)
      #pragma unroll
      for (int ch = 0; ch < 2; ++ch) {
        bf16x8 kf = *(const bf16x8*)&Ks[cur][(nt * 16 + c) * 64 +
                                            ((((ch << 2) | quad) ^ (c & 7)) << 3)];
        #pragma unroll
        for (int rt = 0; rt < 2; ++rt)
          s[rt][nt] = MFMA(qf[rt][ch], kf, s[rt][nt]);
      }

    float mv[4];
    #pragma unroll
    for (int nt = 0; nt < 4; ++nt)
      mv[nt] = mk_[kt * 64 + nt * 16 + c] * LOG2E;

    // ---- p = exp2(s + mask); per-lane l; spill P (R6 0-conflict pattern) ----
    #pragma unroll
    for (int rt = 0; rt < 2; ++rt)
      #pragma unroll
      for (int nt = 0; nt < 4; ++nt)
        #pragma unroll
        for (int reg = 0; reg < 4; ++reg) {
          float p = __builtin_amdgcn_exp2f(s[rt][nt][reg] + mv[nt]);
          lsum[rt][reg] += p;
          int r = 4 * quad + reg;
          int gk = nt * 2 + (c >> 3);
          Ps[wave][rt * 1024 + r * 64 + ((gk ^ (r & 7)) << 3) + (c & 7)] = (bf16)p;
        }
    __asm__ volatile("s_waitcnt lgkmcnt(0)" ::: "memory");  // wave-private order

    // ---- O += P V: V-frags shared across rt ----
    #pragma unroll
    for (int ch = 0; ch < 2; ++ch) {
      bf16x8 pa[2];
      #pragma unroll
      for (int rt = 0; rt < 2; ++rt)
        pa[rt] = *(const bf16x8*)&Ps[wave][rt * 1024 + c * 64 +
                                          ((((ch << 2) | quad) ^ (c & 7)) << 3)];
      #pragma unroll
      for (int nt = 0; nt < 4; ++nt) {
        bf16x8 vf = *(const bf16x8*)&Vs[cur][(nt * 16 + c) * 64 +
                                            ((((ch << 2) | quad) ^ (c & 7)) << 3)];
        #pragma unroll
        for (int rt = 0; rt < 2; ++rt)
          o[rt][nt] = MFMA(pa[rt], vf, o[rt][nt]);
      }
    }
  }

  // ---- final l reduction (16 lanes of the quad) + normalize + store ----
  #pragma unroll
  for (int rt = 0; rt < 2; ++rt)
    #pragma unroll
    for (int reg = 0; reg < 4; ++reg) {
      float l = lsum[rt][reg];
      #pragma unroll
      for (int off = 1; off < 16; off <<= 1) l += __shfl_xor(l, off, 64);
      float inv = 1.0f / l;
      int srow = qblk * 128 + wave * 32 + rt * 16 + 4 * quad + reg;
      #pragma unroll
      for (int nt = 0; nt < 4; ++nt)
        out[((size_t)b * 2048 + srow) * 1024 + h * 64 + nt * 16 + c] =
            o[rt][nt][reg] * inv;
    }
}

// ---------------------------------------------------------------------------
extern "C" void kernel_launch(void* const* d_in, const int* in_sizes, int n_in,
                              void* d_out, int out_size, void* d_ws, size_t ws_size,
                              hipStream_t stream) {
  const float* hs   = (const float*)d_in[0];
  const float* mask = (const float*)d_in[1];
  const float* qw   = (const float*)d_in[2];
  const float* qb   = (const float*)d_in[3];
  const float* kw   = (const float*)d_in[4];
  const float* kb   = (const float*)d_in[5];
  const float* vw   = (const float*)d_in[6];
  const float* vb   = (const float*)d_in[7];
  float* out = (float*)d_out;

  bf16* Xb   = (bf16*)d_ws;                       // 4096x1024      (8 MB)
  bf16* Wt   = Xb + (size_t)4096 * 1024;          // 3x1024x1024    (6 MB)
  bf16* q_ws = Wt + (size_t)3 * 1048576;          // [B,H,S,64]     (8 MB)
  bf16* k_ws = q_ws + (size_t)4096 * 1024;        // [B,H,S,64]     (8 MB)
  bf16* v_ws = k_ws + (size_t)4096 * 1024;        // [B,H,64,S] V^T (8 MB)

  cvt<<<dim3(2816), 256, 0, stream>>>(hs, qw, kw, vw, Xb, Wt);
  qkv_gemm<<<dim3(768), 256, 0, stream>>>(Xb, Wt, qb, kb, vb, q_ws, k_ws, v_ws);
  attn<<<dim3(512), 256, 0, stream>>>(q_ws, k_ws, v_ws, mask, out);
}